// Round 3
// baseline (288.315 us; speedup 1.0000x reference)
//
#include <hip/hip_runtime.h>
#include <hip/hip_bf16.h>

#define D_MODEL 1024
#define NHEAD 16
#define DK 64
#define B_ 4
#define S_ 2048
#define ROWS (B_*S_)          // 8192
#define QKV_N (3*D_MODEL)     // 3072

typedef __attribute__((ext_vector_type(4))) float f32x4;
typedef __attribute__((ext_vector_type(8))) short bf16x8;
typedef unsigned short u16;
typedef unsigned int u32;

__device__ __forceinline__ u16 f2bf(float f) {
    union { float f; u32 u; } x; x.f = f;
    u32 r = x.u + 0x7fffu + ((x.u >> 16) & 1u);
    return (u16)(r >> 16);
}
__device__ __forceinline__ float bf2f(u16 h) {
    union { u32 u; float f; } x; x.u = ((u32)h) << 16;
    return x.f;
}
__device__ __forceinline__ u32 pk2bf(float a, float b) {
    union { __hip_bfloat162 h; u32 u; } c;
    c.h = __float22bfloat162_rn(float2{a, b});
    return c.u;
}

// async global->LDS, 16B per lane.
__device__ __forceinline__ void gload_lds16(const void* g, void* l) {
    __builtin_amdgcn_global_load_lds(
        (const __attribute__((address_space(1))) u32*)g,
        (__attribute__((address_space(3))) u32*)l, 16, 0, 0);
}

// All five f32->bf16 casts in one launch (region-dispatched by blockIdx).
__global__ void cast_all(const float* __restrict__ x,
                         const float* __restrict__ wq, const float* __restrict__ wk,
                         const float* __restrict__ wv, const float* __restrict__ wo,
                         u16* __restrict__ xb, u16* __restrict__ wqkvb, u16* __restrict__ wob) {
    int bi = blockIdx.x;
    const float* src; u16* dst; int local;
    if (bi < 8192)       { src = x;  dst = xb;               local = bi; }
    else if (bi < 9216)  { src = wq; dst = wqkvb;            local = bi - 8192; }
    else if (bi < 10240) { src = wk; dst = wqkvb + 1048576;  local = bi - 9216; }
    else if (bi < 11264) { src = wv; dst = wqkvb + 2097152;  local = bi - 10240; }
    else                 { src = wo; dst = wob;              local = bi - 11264; }
    int i = (local * 256 + (int)threadIdx.x) * 4;
    float4 v = *(const float4*)(src + i);
    ushort4 o; o.x = f2bf(v.x); o.y = f2bf(v.y); o.z = f2bf(v.z); o.w = f2bf(v.w);
    *(ushort4*)(dst + i) = o;
}

// ---------------------------------------------------------------------------
// 8-phase-style GEMM (m201 template adapted): C[m,n] = sum_k A[m,k]*B[n,k].
// BM=128, BN=256, BK=64; 512 threads = 8 waves (2m x 4n); per-wave 64x64 out.
// 3 LDS buffers (144KB dynamic) -> counted vmcnt(6) keeps one K-tile of
// global_load_lds in flight ACROSS barriers (T4). T2 XOR-swizzle applied
// both-sides: pre-swizzled global source (DMA writes linear), same involution
// byte ^= ((row&7)<<4) folded into ds_read addresses. Raw s_barrier +
// compiler fences so hipcc can't inject a vmcnt(0) drain. T5 setprio around
// each 16-MFMA cluster. Accumulation order identical to the old 128x128
// gemm_bt (32 sequential k-chunks per fragment) -> bitwise-same results.
// ---------------------------------------------------------------------------
#define LDSB_PER_BUF 24576   // u16 elems: A 128*64 + B 256*64

template<int CT_BF16>
__global__ __launch_bounds__(512, 2)
void gemm8p(const u16* __restrict__ A, const u16* __restrict__ Bm,
            void* __restrict__ Cp, int M, int N, int K) {
    extern __shared__ u16 ldsb[];
    const int tid = threadIdx.x;
    const int lane = tid & 63, wave = tid >> 6;
    const int wr = wave >> 2, wc = wave & 3;
    const int q4 = lane >> 4, c16 = lane & 15;
    const int csw = (c16 & 7) << 4;

    // XCD-chunked bijective swizzle (nwg % 8 == 0 at both call sites).
    const int gx = gridDim.x;                  // N/256
    const int nwg = gx * gridDim.y;
    int lin = blockIdx.y * gx + blockIdx.x;
    int nl = (lin & 7) * (nwg >> 3) + (lin >> 3);
    const int m0 = (nl / gx) * 128, n0 = (nl % gx) * 256;

    // Staging source coords (pre-swizzled so linear DMA dest == swizzled LDS).
    const int srow = tid >> 3;
    const int scol = ((tid & 7) ^ (srow & 7)) * 8;
    const u16* aS0 = A  + (size_t)(m0 + srow)       * K + scol;
    const u16* aS1 = A  + (size_t)(m0 + 64 + srow)  * K + scol;
    const u16* bS0 = Bm + (size_t)(n0 + srow)       * K + scol;
    const u16* bS1 = Bm + (size_t)(n0 + 64 + srow)  * K + scol;
    const u16* bS2 = Bm + (size_t)(n0 + 128 + srow) * K + scol;
    const u16* bS3 = Bm + (size_t)(n0 + 192 + srow) * K + scol;
    const int tid8 = tid * 8;                  // u16 elems = 16B per thread

    const int NT = K >> 6;                     // 16 for K=1024
    f32x4 acc[4][4] = {};

#define STAGE_A(t2, sp) do { \
    u16* Ad_ = ldsb + (sp) * LDSB_PER_BUF; \
    u16* Bd_ = Ad_ + 8192; \
    const size_t ko_ = (size_t)(t2) * 64; \
    gload_lds16(aS0 + ko_, Ad_ + tid8); \
    gload_lds16(aS1 + ko_, Ad_ + 4096 + tid8); \
    gload_lds16(bS0 + ko_, Bd_ + tid8); \
} while (0)
#define STAGE_B(t2, sp) do { \
    u16* Bd_ = ldsb + (sp) * LDSB_PER_BUF + 8192; \
    const size_t ko_ = (size_t)(t2) * 64; \
    gload_lds16(bS1 + ko_, Bd_ + 4096 + tid8); \
    gload_lds16(bS2 + ko_, Bd_ + 8192 + tid8); \
    gload_lds16(bS3 + ko_, Bd_ + 12288 + tid8); \
} while (0)
// swizzled ds_read of one bf16x8 fragment: logical (row, k-chunk kk)
#define RD(base, row, kk) \
    (*(const bf16x8*)((const char*)(base) + (row) * 128 + (((kk) * 64 + q4 * 16) ^ csw)))

    // prologue: tiles 0,1 into bufs 0,1; wait tile0 (oldest 6), barrier.
    STAGE_A(0, 0); STAGE_B(0, 0);
    STAGE_A(1, 1); STAGE_B(1, 1);
    asm volatile("s_waitcnt vmcnt(6)" ::: "memory");
    __builtin_amdgcn_s_barrier();

    int rp = 0;
    for (int t = 0; t < NT; ++t) {
        const u16* Ab = ldsb + rp * LDSB_PER_BUF;
        const u16* Bb = Ab + 8192;
        const int sp = (rp >= 1) ? rp - 1 : 2;       // (t+2)%3
        const bool st = (t + 2) < NT;

        // ---- phase 0: read af(mt 0,1) + all bf; issue 3 stage loads ----
        bf16x8 a00 = RD(Ab, wr * 64 + 0  + c16, 0), a01 = RD(Ab, wr * 64 + 0  + c16, 1);
        bf16x8 a10 = RD(Ab, wr * 64 + 16 + c16, 0), a11 = RD(Ab, wr * 64 + 16 + c16, 1);
        bf16x8 b00 = RD(Bb, wc * 64 + 0  + c16, 0), b01 = RD(Bb, wc * 64 + 0  + c16, 1);
        bf16x8 b10 = RD(Bb, wc * 64 + 16 + c16, 0), b11 = RD(Bb, wc * 64 + 16 + c16, 1);
        bf16x8 b20 = RD(Bb, wc * 64 + 32 + c16, 0), b21 = RD(Bb, wc * 64 + 32 + c16, 1);
        bf16x8 b30 = RD(Bb, wc * 64 + 48 + c16, 0), b31 = RD(Bb, wc * 64 + 48 + c16, 1);
        if (st) STAGE_A(t + 2, sp);
        asm volatile("" ::: "memory");
        __builtin_amdgcn_s_barrier();
        __builtin_amdgcn_s_setprio(1);
        acc[0][0] = __builtin_amdgcn_mfma_f32_16x16x32_bf16(a00, b00, acc[0][0], 0, 0, 0);
        acc[0][0] = __builtin_amdgcn_mfma_f32_16x16x32_bf16(a01, b01, acc[0][0], 0, 0, 0);
        acc[0][1] = __builtin_amdgcn_mfma_f32_16x16x32_bf16(a00, b10, acc[0][1], 0, 0, 0);
        acc[0][1] = __builtin_amdgcn_mfma_f32_16x16x32_bf16(a01, b11, acc[0][1], 0, 0, 0);
        acc[0][2] = __builtin_amdgcn_mfma_f32_16x16x32_bf16(a00, b20, acc[0][2], 0, 0, 0);
        acc[0][2] = __builtin_amdgcn_mfma_f32_16x16x32_bf16(a01, b21, acc[0][2], 0, 0, 0);
        acc[0][3] = __builtin_amdgcn_mfma_f32_16x16x32_bf16(a00, b30, acc[0][3], 0, 0, 0);
        acc[0][3] = __builtin_amdgcn_mfma_f32_16x16x32_bf16(a01, b31, acc[0][3], 0, 0, 0);
        acc[1][0] = __builtin_amdgcn_mfma_f32_16x16x32_bf16(a10, b00, acc[1][0], 0, 0, 0);
        acc[1][0] = __builtin_amdgcn_mfma_f32_16x16x32_bf16(a11, b01, acc[1][0], 0, 0, 0);
        acc[1][1] = __builtin_amdgcn_mfma_f32_16x16x32_bf16(a10, b10, acc[1][1], 0, 0, 0);
        acc[1][1] = __builtin_amdgcn_mfma_f32_16x16x32_bf16(a11, b11, acc[1][1], 0, 0, 0);
        acc[1][2] = __builtin_amdgcn_mfma_f32_16x16x32_bf16(a10, b20, acc[1][2], 0, 0, 0);
        acc[1][2] = __builtin_amdgcn_mfma_f32_16x16x32_bf16(a11, b21, acc[1][2], 0, 0, 0);
        acc[1][3] = __builtin_amdgcn_mfma_f32_16x16x32_bf16(a10, b30, acc[1][3], 0, 0, 0);
        acc[1][3] = __builtin_amdgcn_mfma_f32_16x16x32_bf16(a11, b31, acc[1][3], 0, 0, 0);
        __builtin_amdgcn_s_setprio(0);
        asm volatile("" ::: "memory");
        __builtin_amdgcn_s_barrier();

        // ---- phase 1: read af(mt 2,3), bf stays in regs; 3 stage loads ----
        bf16x8 a20 = RD(Ab, wr * 64 + 32 + c16, 0), a21 = RD(Ab, wr * 64 + 32 + c16, 1);
        bf16x8 a30 = RD(Ab, wr * 64 + 48 + c16, 0), a31 = RD(Ab, wr * 64 + 48 + c16, 1);
        if (st) STAGE_B(t + 2, sp);
        asm volatile("" ::: "memory");
        __builtin_amdgcn_s_barrier();
        __builtin_amdgcn_s_setprio(1);
        acc[2][0] = __builtin_amdgcn_mfma_f32_16x16x32_bf16(a20, b00, acc[2][0], 0, 0, 0);
        acc[2][0] = __builtin_amdgcn_mfma_f32_16x16x32_bf16(a21, b01, acc[2][0], 0, 0, 0);
        acc[2][1] = __builtin_amdgcn_mfma_f32_16x16x32_bf16(a20, b10, acc[2][1], 0, 0, 0);
        acc[2][1] = __builtin_amdgcn_mfma_f32_16x16x32_bf16(a21, b11, acc[2][1], 0, 0, 0);
        acc[2][2] = __builtin_amdgcn_mfma_f32_16x16x32_bf16(a20, b20, acc[2][2], 0, 0, 0);
        acc[2][2] = __builtin_amdgcn_mfma_f32_16x16x32_bf16(a21, b21, acc[2][2], 0, 0, 0);
        acc[2][3] = __builtin_amdgcn_mfma_f32_16x16x32_bf16(a20, b30, acc[2][3], 0, 0, 0);
        acc[2][3] = __builtin_amdgcn_mfma_f32_16x16x32_bf16(a21, b31, acc[2][3], 0, 0, 0);
        acc[3][0] = __builtin_amdgcn_mfma_f32_16x16x32_bf16(a30, b00, acc[3][0], 0, 0, 0);
        acc[3][0] = __builtin_amdgcn_mfma_f32_16x16x32_bf16(a31, b01, acc[3][0], 0, 0, 0);
        acc[3][1] = __builtin_amdgcn_mfma_f32_16x16x32_bf16(a30, b10, acc[3][1], 0, 0, 0);
        acc[3][1] = __builtin_amdgcn_mfma_f32_16x16x32_bf16(a31, b11, acc[3][1], 0, 0, 0);
        acc[3][2] = __builtin_amdgcn_mfma_f32_16x16x32_bf16(a30, b20, acc[3][2], 0, 0, 0);
        acc[3][2] = __builtin_amdgcn_mfma_f32_16x16x32_bf16(a31, b21, acc[3][2], 0, 0, 0);
        acc[3][3] = __builtin_amdgcn_mfma_f32_16x16x32_bf16(a30, b30, acc[3][3], 0, 0, 0);
        acc[3][3] = __builtin_amdgcn_mfma_f32_16x16x32_bf16(a31, b31, acc[3][3], 0, 0, 0);
        __builtin_amdgcn_s_setprio(0);
        // counted vmcnt at the K-tile boundary: oldest 6 (= tile t+1) done;
        // tile t+2's 6 loads stay in flight across the barrier.
        if (st)                asm volatile("s_waitcnt vmcnt(6)" ::: "memory");
        else if (t + 1 < NT)   asm volatile("s_waitcnt vmcnt(0)" ::: "memory");
        asm volatile("" ::: "memory");
        __builtin_amdgcn_s_barrier();
        rp = (rp >= 2) ? 0 : rp + 1;
    }
#undef STAGE_A
#undef STAGE_B
#undef RD

    #pragma unroll
    for (int mt = 0; mt < 4; ++mt)
        #pragma unroll
        for (int nt = 0; nt < 4; ++nt)
            #pragma unroll
            for (int r = 0; r < 4; ++r) {
                int row = m0 + wr * 64 + mt * 16 + q4 * 4 + r;
                int col = n0 + wc * 64 + nt * 16 + c16;
                float v = acc[mt][nt][r];
                if (CT_BF16) ((u16*)Cp)[(size_t)row * N + col] = f2bf(v);
                else         ((float*)Cp)[(size_t)row * N + col] = v;
            }
}

// RoPE in place on Q,K halves of QKV [8192, 3072] bf16.
__global__ void rope_kernel(u16* __restrict__ QKV, const int* __restrict__ pos) {
    int idx = blockIdx.x * blockDim.x + threadIdx.x;
    if (idx >= ROWS * 1024) return;
    int row = idx >> 10;
    int t = idx & 1023;
    int part = t >> 9;         // 0 = Q, 1 = K
    int p = t & 511;
    int h = p >> 5, i = p & 31;
    int col = part * D_MODEL + h * 64 + 2 * i;
    int s = row & (S_ - 1);
    float inv_freq = __expf(-(float)i * 0.2878231366242557f); // 10000^(-i/32)
    float ang = (float)pos[s] * inv_freq;
    float sn, cs;
    sincosf(ang, &sn, &cs);
    u16* ptr = QKV + (size_t)row * QKV_N + col;
    float xe = bf2f(ptr[0]), xo = bf2f(ptr[1]);
    ptr[0] = f2bf(cs * xe - sn * xo);
    ptr[1] = f2bf(sn * xe + cs * xo);
}

// Balanced schedule: 12 groups per bh, each exactly 44 processes.
__device__ __constant__ signed char g_pairs[32] = {
    11,31, 12,30, 13,29, 14,28, 15,27, 16,26, 17,25, 18,24, 19,23, 20,22,
    10,21, 0,9,  7,8,  5,6,  3,4,  1,2 };
__device__ __constant__ unsigned char g_poff[13] = {0,1,2,3,4,5,6,7,8,9,10,12,16};

// FIXED-OFFSET softmax: p = exp2(s_raw*C - T). Scale cancels in O = (P V)/l.
__device__ __forceinline__ void softmax_p(
    f32x4 (&sf)[4], u16* __restrict__ Psw, float& l_i,
    int qrow0, int kt, bool diag, int c16, int q4, bf16x8 (&pf)[2]) {
    if (diag) {
        const int qg = qrow0 + c16;
        #pragma unroll
        for (int nt = 0; nt < 4; ++nt)
            #pragma unroll
            for (int r = 0; r < 4; ++r) {
                int kg = kt * 64 + nt * 16 + q4 * 4 + r;
                if (kg > qg) sf[nt][r] = -1e30f;
            }
    }
    const float C = 0.18033688011112042f;   // 0.125 * log2(e)
    const float T = 46.16624130844683f;     // 32 * log2(e)
    float rs = 0.f;
    #pragma unroll
    for (int nt = 0; nt < 4; ++nt) {
        float p0 = exp2f(__builtin_fmaf(sf[nt][0], C, -T));
        float p1 = exp2f(__builtin_fmaf(sf[nt][1], C, -T));
        float p2 = exp2f(__builtin_fmaf(sf[nt][2], C, -T));
        float p3 = exp2f(__builtin_fmaf(sf[nt][3], C, -T));
        rs += (p0 + p1) + (p2 + p3);
        uint2 w; w.x = pk2bf(p0, p1); w.y = pk2bf(p2, p3);
        *(uint2*)&Psw[c16 * 72 + nt * 16 + q4 * 4] = w;   // P[qrow][key]
    }
    l_i += rs;
    pf[0] = *(const bf16x8*)&Psw[c16 * 72 + q4 * 8];
    pf[1] = *(const bf16x8*)&Psw[c16 * 72 + 32 + q4 * 8];
}

// Flash attention (round-2 version, unchanged: merged strips, DMA-K with
// XOR swizzle, XCD-chunked grid).
__global__ __launch_bounds__(256, 3)
void attn_kernel(const u16* __restrict__ QKV, u16* __restrict__ O) {
    __shared__ u16 Kt[2][64 * 64];
    __shared__ u16 Vt[2][64 * 72];
    __shared__ u16 Ps[4][16 * 72];
    __shared__ float aS[4][16];
    const int tid = threadIdx.x, lane = tid & 63, wave = tid >> 6;
    const int q4 = lane >> 4, c16 = lane & 15;
    int lin = blockIdx.y * 12 + blockIdx.x;
    int nl = (lin & 7) * 96 + (lin >> 3);
    const int g = nl % 12;
    const int bh = nl / 12;
    const int b = bh >> 4, h = bh & 15;
    const size_t rowbase = (size_t)b * S_ * QKV_N;

    const int kr0 = wave * 16 + (lane >> 3);
    const int kcsw = ((lane & 7) ^ (lane >> 3)) * 8;
    const u16* ksrc0 = QKV + rowbase + (size_t)kr0 * QKV_N + D_MODEL + h * 64 + kcsw;
    const int ksw = (c16 & 7) << 4;
    const int koff0 = (q4 * 16) ^ ksw;
    const int koff1 = (64 + q4 * 16) ^ ksw;

    const int kp = tid & 31, dg = tid >> 5;
    const u16* vbase = QKV + rowbase + (size_t)(2 * kp) * QKV_N + 2 * D_MODEL + h * 64 + dg * 8;

    for (int pi = g_poff[g]; pi < g_poff[g + 1]; ++pi) {
        const int tA = g_pairs[2 * pi], tB = g_pairs[2 * pi + 1];

        bf16x8 qfA[2], qfB[2];
        {
            const u16* qa = QKV + rowbase + (size_t)(tA * 64 + wave * 16 + c16) * QKV_N + h * 64 + q4 * 8;
            qfA[0] = *(const bf16x8*)qa;
            qfA[1] = *(const bf16x8*)(qa + 32);
            const u16* qb = QKV + rowbase + (size_t)(tB * 64 + wave * 16 + c16) * QKV_N + h * 64 + q4 * 8;
            qfB[0] = *(const bf16x8*)qb;
            qfB[1] = *(const bf16x8*)(qb + 32);
        }
        f32x4 ofA[4] = {}, ofB[4] = {};
        float lA = 0.f, lB = 0.f;
        const int qrowA = tA * 64 + wave * 16;
        const int qrowB = tB * 64 + wave * 16;

        gload_lds16(ksrc0, (char*)Kt[0] + wave * 2048 + lane * 16);
        gload_lds16(ksrc0 + (size_t)8 * QKV_N, (char*)Kt[0] + wave * 2048 + 1024 + lane * 16);
        bf16x8 va = *(const bf16x8*)vbase, vb = *(const bf16x8*)(vbase + QKV_N);
        #pragma unroll
        for (int j = 0; j < 8; ++j) {
            u32 w = ((u32)(u16)va[j]) | (((u32)(u16)vb[j]) << 16);
            *(u32*)&Vt[0][(dg * 8 + j) * 72 + 2 * kp] = w;
        }
        __syncthreads();

        int bb = 0;
        for (int kt = 0; kt <= tB; ++kt) {
            const bool more = kt < tB;
            const bool aAct = kt <= tA;
            if (more) {
                const u16* s0 = ksrc0 + (size_t)(kt + 1) * 64 * QKV_N;
                gload_lds16(s0, (char*)Kt[bb ^ 1] + wave * 2048 + lane * 16);
                gload_lds16(s0 + (size_t)8 * QKV_N, (char*)Kt[bb ^ 1] + wave * 2048 + 1024 + lane * 16);
                const u16* vp_ = vbase + (size_t)(kt + 1) * 64 * QKV_N;
                va = *(const bf16x8*)vp_;  vb = *(const bf16x8*)(vp_ + QKV_N);
            }

            f32x4 sfA[4] = {}, sfB[4] = {};
            const char* Kb = (const char*)Kt[bb];
            __builtin_amdgcn_s_setprio(1);
            if (aAct) {
                #pragma unroll
                for (int nt = 0; nt < 4; ++nt) {
                    bf16x8 kf0 = *(const bf16x8*)(Kb + nt * 2048 + c16 * 128 + koff0);
                    bf16x8 kf1 = *(const bf16x8*)(Kb + nt * 2048 + c16 * 128 + koff1);
                    sfB[nt] = __builtin_amdgcn_mfma_f32_16x16x32_bf16(kf0, qfB[0], sfB[nt], 0, 0, 0);
                    sfB[nt] = __builtin_amdgcn_mfma_f32_16x16x32_bf16(kf1, qfB[1], sfB[nt], 0, 0, 0);
                    sfA[nt] = __builtin_amdgcn_mfma_f32_16x16x32_bf16(kf0, qfA[0], sfA[nt], 0, 0, 0);
                    sfA[nt] = __builtin_amdgcn_mfma_f32_16x16x32_bf16(kf1, qfA[1], sfA[nt], 0, 0, 0);
                }
            } else {
                #pragma unroll
                for (int nt = 0; nt < 4; ++nt) {
                    bf16x8 kf0 = *(const bf16x8*)(Kb + nt * 2048 + c16 * 128 + koff0);
                    bf16x8 kf1 = *(const bf16x8*)(Kb + nt * 2048 + c16 * 128 + koff1);
                    sfB[nt] = __builtin_amdgcn_mfma_f32_16x16x32_bf16(kf0, qfB[0], sfB[nt], 0, 0, 0);
                    sfB[nt] = __builtin_amdgcn_mfma_f32_16x16x32_bf16(kf1, qfB[1], sfB[nt], 0, 0, 0);
                }
            }
            __builtin_amdgcn_s_setprio(0);

            bf16x8 pfA[2], pfB[2];
            if (aAct) softmax_p(sfA, Ps[wave], lA, qrowA, kt, kt == tA, c16, q4, pfA);
            softmax_p(sfB, Ps[wave], lB, qrowB, kt, kt == tB, c16, q4, pfB);

            if (more) {
                #pragma unroll
                for (int j = 0; j < 8; ++j) {
                    u32 w = ((u32)(u16)va[j]) | (((u32)(u16)vb[j]) << 16);
                    *(u32*)&Vt[bb ^ 1][(dg * 8 + j) * 72 + 2 * kp] = w;
                }
            }

            const u16* Vb = Vt[bb];
            __builtin_amdgcn_s_setprio(1);
            if (aAct) {
                #pragma unroll
                for (int kk = 0; kk < 2; ++kk)
                    #pragma unroll
                    for (int nt = 0; nt < 4; ++nt) {
                        bf16x8 vf = *(const bf16x8*)&Vb[(nt * 16 + c16) * 72 + kk * 32 + q4 * 8];
                        ofB[nt] = __builtin_amdgcn_mfma_f32_16x16x32_bf16(pfB[kk], vf, ofB[nt], 0, 0, 0);
                        ofA[nt] = __builtin_amdgcn_mfma_f32_16x16x32_bf16(pfA[kk], vf, ofA[nt], 0, 0, 0);
                    }
            } else {
                #pragma unroll
                for (int kk = 0; kk < 2; ++kk)
                    #pragma unroll
                    for (int nt = 0; nt < 4; ++nt) {
                        bf16x8 vf = *(const bf16x8*)&Vb[(nt * 16 + c16) * 72 + kk * 32 + q4 * 8];
                        ofB[nt] = __builtin_amdgcn_mfma_f32_16x16x32_bf16(pfB[kk], vf, ofB[nt], 0, 0, 0);
                    }
            }
            __builtin_amdgcn_s_setprio(0);

            __syncthreads();
            bb ^= 1;
        }

        lA += __shfl_xor(lA, 16, 64); lA += __shfl_xor(lA, 32, 64);
        lB += __shfl_xor(lB, 16, 64); lB += __shfl_xor(lB, 32, 64);
        if (q4 == 0) aS[wave][c16] = lA;
        f32x4 lv = *(const f32x4*)&aS[wave][q4 * 4];
        #pragma unroll
        for (int r = 0; r < 4; ++r) {
            float inv = 1.0f / lv[r];
            int row = b * S_ + tA * 64 + wave * 16 + q4 * 4 + r;
            #pragma unroll
            for (int nt = 0; nt < 4; ++nt)
                O[(size_t)row * D_MODEL + h * 64 + nt * 16 + c16] = f2bf(ofA[nt][r] * inv);
        }
        if (q4 == 0) aS[wave][c16] = lB;
        f32x4 lv2 = *(const f32x4*)&aS[wave][q4 * 4];
        #pragma unroll
        for (int r = 0; r < 4; ++r) {
            float inv = 1.0f / lv2[r];
            int row = b * S_ + tB * 64 + wave * 16 + q4 * 4 + r;
            #pragma unroll
            for (int nt = 0; nt < 4; ++nt)
                O[(size_t)row * D_MODEL + h * 64 + nt * 16 + c16] = f2bf(ofB[nt][r] * inv);
        }
    }
}

extern "C" void kernel_launch(void* const* d_in, const int* in_sizes, int n_in,
                              void* d_out, int out_size, void* d_ws, size_t ws_size,
                              hipStream_t stream) {
    const float* x  = (const float*)d_in[0];
    const int*   tp = (const int*)d_in[1];
    const float* Wq = (const float*)d_in[2];
    const float* Wk = (const float*)d_in[3];
    const float* Wv = (const float*)d_in[4];
    const float* Wo = (const float*)d_in[5];
    float* out = (float*)d_out;

    char* ws = (char*)d_ws;
    u16* xb    = (u16*)(ws);                 // 16,777,216 B
    u16* Wqkvb = (u16*)(ws + 16777216);      //  6,291,456 B
    u16* Wob   = (u16*)(ws + 23068672);      //  2,097,152 B
    u16* QKV   = (u16*)(ws + 25165824);      // 50,331,648 B
    u16* Ob    = (u16*)(ws + 75497472);      // 16,777,216 B  (total 92,274,688 B)

    // 144KB dynamic LDS for the 3-buffer GEMM (above the 64KB static cap).
    static bool attr_set = false;
    if (!attr_set) {
        hipFuncSetAttribute((const void*)gemm8p<1>,
                            hipFuncAttributeMaxDynamicSharedMemorySize, 147456);
        hipFuncSetAttribute((const void*)gemm8p<0>,
                            hipFuncAttributeMaxDynamicSharedMemorySize, 147456);
        attr_set = true;
    }

    cast_all<<<dim3(12288), dim3(256), 0, stream>>>(x, Wq, Wk, Wv, Wo, xb, Wqkvb, Wob);

    gemm8p<1><<<dim3(QKV_N / 256, ROWS / 128), dim3(512), 147456, stream>>>(
        xb, Wqkvb, (void*)QKV, ROWS, QKV_N, D_MODEL);

    rope_kernel<<<dim3(ROWS * 1024 / 256), dim3(256), 0, stream>>>(QKV, tp);

    attn_kernel<<<dim3(12, B_ * NHEAD), dim3(256), 0, stream>>>(QKV, Ob);

    gemm8p<0><<<dim3(D_MODEL / 256, ROWS / 128), dim3(512), 147456, stream>>>(
        Ob, Wob, (void*)out, ROWS, D_MODEL, D_MODEL);
}